// Round 3
// baseline (728.906 us; speedup 1.0000x reference)
//
#include <hip/hip_runtime.h>
#include <math.h>

#define DIM 128
#define NRES 262144

typedef __attribute__((ext_vector_type(8))) short short8;
typedef __attribute__((ext_vector_type(4))) float f32x4;

__device__ __forceinline__ float sigmoidf_(float x) {
    return 1.0f / (1.0f + __expf(-x));
}
__device__ __forceinline__ float tanhf_(float x) {
    return 1.0f - 2.0f / (__expf(2.0f * x) + 1.0f);
}
__device__ __forceinline__ unsigned short f2bf(float f) {
    unsigned int u = __float_as_uint(f);
    unsigned int r = u + 0x7FFFu + ((u >> 16) & 1u);
    return (unsigned short)(r >> 16);
}
__device__ __forceinline__ float bf2f(unsigned short s) {
    return __uint_as_float(((unsigned int)s) << 16);
}

// W f32 [640][256] -> bf16 [640][256]
__global__ void convert_w_kernel(const float* __restrict__ W, unsigned short* __restrict__ Wb) {
    int i = blockIdx.x * 256 + threadIdx.x;  // 40960 threads x 4 elems
    float4 v = ((const float4*)W)[i];
    unsigned short o[4] = {f2bf(v.x), f2bf(v.y), f2bf(v.z), f2bf(v.w)};
    *(ushort4*)(Wb + i * 4) = *(ushort4*)o;
}

// One tree-LSTM level. A = x_in viewed as [n_par][256] (parent rows = concat of
// 2 child h rows, contiguous). BM=128 rows/block, 512 thr = 8 waves
// (mh = wid>>2 picks M-half of 64, ws = wid&3 picks 32-dim gate-aligned N-slice
// so the LSTM epilogue is wave-local). A staged in LDS (64KB) with chunk-XOR
// swizzle (chunk ^= row&7) to break the stride-512B bank conflict; B (W) read
// as fragments from L2. Non-FIRST staging uses global_load_lds width=16 with
// the inverse swizzle applied to the per-lane GLOBAL source (rule: linear dest).
template<bool FIRST>
__global__ __launch_bounds__(512, 1)
void level_kernel(const void* __restrict__ x_in,
                  const float* __restrict__ c_in,
                  const unsigned short* __restrict__ Wb,
                  const float* __restrict__ b,
                  unsigned short* __restrict__ h_out,
                  float* __restrict__ c_out,
                  int n_par) {
    __shared__ unsigned short As[128 * 256];  // 64 KB

    const int t = threadIdx.x;
    const int lane = t & 63;
    const int wid = t >> 6;   // 0..7
    const int ws = wid & 3;   // N-slice
    const int mh = wid >> 2;  // M-half
    const int col = lane & 15;
    const int kg = lane >> 4;
    const int m0 = blockIdx.x * 128;

    if (FIRST) {
        // leaf is f32: reg-stage + convert + swizzled ds_write
        const float* xf = (const float*)x_in + (size_t)m0 * 256;
        #pragma unroll
        for (int i = 0; i < 8; ++i) {
            int j = i * 512 + t;       // 16B-chunk index 0..4095
            int r = j >> 5;            // row 0..127
            int c = j & 31;            // chunk within row
            const float* s = xf + r * 256 + c * 8;
            float4 u0 = *(const float4*)s;
            float4 u1 = *(const float4*)(s + 4);
            unsigned short o[8] = {f2bf(u0.x), f2bf(u0.y), f2bf(u0.z), f2bf(u0.w),
                                   f2bf(u1.x), f2bf(u1.y), f2bf(u1.z), f2bf(u1.w)};
            *(short8*)&As[r * 256 + ((c ^ (r & 7)) * 8)] = *(short8*)o;
        }
    } else {
        const unsigned short* xb = (const unsigned short*)x_in + (size_t)m0 * 256;
        #pragma unroll
        for (int i = 0; i < 8; ++i) {
            int j0 = i * 512 + wid * 64;   // wave-uniform chunk base
            int j = j0 + lane;
            int r = j >> 5;
            int c = j & 31;
            __builtin_amdgcn_global_load_lds(
                (const __attribute__((address_space(1))) unsigned int*)(xb + (size_t)r * 256 + ((c ^ (r & 7)) * 8)),
                (__attribute__((address_space(3))) unsigned int*)&As[(size_t)j0 * 8],
                16, 0, 0);
        }
    }
    __syncthreads();

    f32x4 acc[4][10];  // [m-frag][g*2+nn]
    #pragma unroll
    for (int mf = 0; mf < 4; ++mf)
        #pragma unroll
        for (int nf = 0; nf < 10; ++nf)
            acc[mf][nf] = (f32x4){0.f, 0.f, 0.f, 0.f};

    const unsigned short* wbase = Wb + (size_t)(ws * 32 + col) * 256 + kg * 8;

    #pragma unroll
    for (int kc = 0; kc < 8; ++kc) {
        short8 a[4];
        #pragma unroll
        for (int mf = 0; mf < 4; ++mf) {
            int ar = mh * 64 + mf * 16 + col;
            int q = (kg + kc * 4) ^ (ar & 7);
            a[mf] = *(const short8*)&As[ar * 256 + q * 8];
        }
        #pragma unroll
        for (int g = 0; g < 5; ++g) {
            #pragma unroll
            for (int nn = 0; nn < 2; ++nn) {
                short8 bf = *(const short8*)(wbase + (size_t)(g * 128 + nn * 16) * 256 + kc * 32);
                const int nf = g * 2 + nn;
                #pragma unroll
                for (int mf = 0; mf < 4; ++mf)
                    acc[mf][nf] = __builtin_amdgcn_mfma_f32_16x16x32_bf16(a[mf], bf, acc[mf][nf], 0, 0, 0);
            }
        }
    }

    float bias[5][2];
    #pragma unroll
    for (int g = 0; g < 5; ++g)
        #pragma unroll
        for (int nn = 0; nn < 2; ++nn)
            bias[g][nn] = b[g * 128 + ws * 32 + nn * 16 + col];

    #pragma unroll
    for (int mf = 0; mf < 4; ++mf) {
        #pragma unroll
        for (int r = 0; r < 4; ++r) {
            const int P = m0 + mh * 64 + mf * 16 + kg * 4 + r;
            if (P < n_par) {
                #pragma unroll
                for (int nn = 0; nn < 2; ++nn) {
                    const int d = ws * 32 + nn * 16 + col;
                    float iv = sigmoidf_(acc[mf][0 + nn][r] + bias[0][nn]);
                    float fl = sigmoidf_(acc[mf][2 + nn][r] + bias[1][nn]);
                    float fr = sigmoidf_(acc[mf][4 + nn][r] + bias[2][nn]);
                    float ov = sigmoidf_(acc[mf][6 + nn][r] + bias[3][nn]);
                    float gv = tanhf_(acc[mf][8 + nn][r] + bias[4][nn]);
                    float cl = 0.f, cr = 0.f;
                    if (!FIRST) {
                        cl = c_in[(size_t)(2 * P) * 128 + d];
                        cr = c_in[(size_t)(2 * P + 1) * 128 + d];
                    }
                    float cn = fl * cl + fr * cr + iv * gv;
                    float hn = ov * tanhf_(cn);
                    c_out[(size_t)P * 128 + d] = cn;
                    h_out[(size_t)P * 128 + d] = f2bf(hn);
                }
            }
        }
    }
}

// out[0:128] = mean of 4 bf16 roots; out[128:256] = 0
__global__ void root_kernel(const unsigned short* __restrict__ hf, float* __restrict__ out) {
    int t = threadIdx.x;
    if (t < 128) {
        out[t] = 0.25f * (bf2f(hf[t]) + bf2f(hf[128 + t]) + bf2f(hf[256 + t]) + bf2f(hf[384 + t]));
    } else if (t < 256) {
        out[t] = 0.0f;
    }
}

// leaves output row r -> [leaf_emb[r] (128 f32) | zeros (128)]
__global__ void copy_leaves_kernel(const float* __restrict__ leaf, float* __restrict__ out) {
    const float4* lf4 = (const float4*)leaf;
    float4* of4 = (float4*)(out + 256);
    const size_t total = (size_t)NRES * 64;
    for (size_t v = (size_t)blockIdx.x * blockDim.x + threadIdx.x; v < total;
         v += (size_t)gridDim.x * blockDim.x) {
        size_t r = v >> 6;
        int c = (int)(v & 63);
        float4 val = (c < 32) ? lf4[(r << 5) + c] : make_float4(0.f, 0.f, 0.f, 0.f);
        of4[v] = val;
    }
}

extern "C" void kernel_launch(void* const* d_in, const int* in_sizes, int n_in,
                              void* d_out, int out_size, void* d_ws, size_t ws_size,
                              hipStream_t stream) {
    const float* leaf = (const float*)d_in[0];
    const float* W_up = (const float*)d_in[1];
    const float* b_up = (const float*)d_in[2];
    float* out = (float*)d_out;
    char* base = (char*)d_out;

    // Scratch carved from d_out (fully overwritten by root + copy at the end):
    float* cA = (float*)(base);                               // 64 MiB
    float* cB = (float*)(base + 67108864);                    // 32 MiB
    unsigned short* hA = (unsigned short*)(base + 100663296); // 32 MiB
    unsigned short* hB = (unsigned short*)(base + 134217728); // 16 MiB
    unsigned short* Wb = (unsigned short*)(base + 150994944); // 320 KiB

    convert_w_kernel<<<160, 256, 0, stream>>>(W_up, Wb);

    int n_par = NRES / 2;  // 131072
    level_kernel<true><<<n_par / 128, 512, 0, stream>>>(leaf, nullptr, Wb, b_up, hA, cA, n_par);

    const unsigned short* hin = hA;
    const float* cin = cA;
    unsigned short* ho = hB;
    float* co = cB;
    for (int lvl = 2; lvl <= 16; ++lvl) {
        n_par >>= 1;
        int blocks = (n_par + 127) / 128;
        if (blocks < 1) blocks = 1;
        level_kernel<false><<<blocks, 512, 0, stream>>>(hin, cin, Wb, b_up, ho, co, n_par);
        const unsigned short* th = hin;
        const float* tc = cin;
        hin = ho; cin = co;
        ho = (unsigned short*)th; co = (float*)tc;
    }
    // 16 levels -> final 4 roots are in hB (hin points there now)
    root_kernel<<<1, 256, 0, stream>>>(hin, out);
    copy_leaves_kernel<<<4096, 256, 0, stream>>>(leaf, out);
}

// Round 4
// 564.799 us; speedup vs baseline: 1.2906x; 1.2906x over previous
//
#include <hip/hip_runtime.h>
#include <math.h>

#define DIM 128
#define NRES 262144

typedef __attribute__((ext_vector_type(8))) short short8;
typedef __attribute__((ext_vector_type(4))) float f32x4;

__device__ __forceinline__ float sigmoidf_(float x) {
    return 1.0f / (1.0f + __expf(-x));
}
__device__ __forceinline__ float tanhf_(float x) {
    return 1.0f - 2.0f / (__expf(2.0f * x) + 1.0f);
}
__device__ __forceinline__ unsigned short f2bf(float f) {
    unsigned int u = __float_as_uint(f);
    unsigned int r = u + 0x7FFFu + ((u >> 16) & 1u);
    return (unsigned short)(r >> 16);
}
__device__ __forceinline__ float bf2f(unsigned short s) {
    return __uint_as_float(((unsigned int)s) << 16);
}

// W f32 [640][256] -> bf16 [640][256]
__global__ void convert_w_kernel(const float* __restrict__ W, unsigned short* __restrict__ Wb) {
    int i = blockIdx.x * 256 + threadIdx.x;
    float4 v = ((const float4*)W)[i];
    unsigned short o[4] = {f2bf(v.x), f2bf(v.y), f2bf(v.z), f2bf(v.w)};
    *(ushort4*)(Wb + i * 4) = *(ushort4*)o;
}

// One tree-LSTM level. A = x_in viewed as [n_par][256]. BM=64 rows/block,
// 512 thr = 8 waves, wave w owns the 16-wide d-slice [16w,16w+16) across ALL
// 5 gates (wave-local epilogue). acc[4][5] = 80 regs/lane -> 2 waves/SIMD.
// A staged in LDS (32 KB) with chunk-XOR swizzle (q ^= row&7); B (W) read as
// 16B fragments from L2.
template<bool FIRST>
__global__ __launch_bounds__(512)
void level_kernel(const void* __restrict__ x_in,
                  const float* __restrict__ c_in,
                  const unsigned short* __restrict__ Wb,
                  const float* __restrict__ b,
                  unsigned short* __restrict__ h_out,
                  float* __restrict__ c_out,
                  int n_par) {
    __shared__ unsigned short As[64 * 256];  // 32 KB

    const int t = threadIdx.x;
    const int lane = t & 63;
    const int wid = t >> 6;   // 0..7 = d-slice
    const int col = lane & 15;
    const int kg = lane >> 4;
    const int m0 = blockIdx.x * 64;

    if (FIRST) {
        // leaf is f32: reg-stage + convert + swizzled ds_write
        const float* xf = (const float*)x_in + (size_t)m0 * 256;
        #pragma unroll
        for (int i = 0; i < 4; ++i) {
            int j = i * 512 + t;       // 16B-chunk index 0..2047
            int r = j >> 5;            // row 0..63
            int c = j & 31;            // chunk within row
            const float* s = xf + r * 256 + c * 8;
            float4 u0 = *(const float4*)s;
            float4 u1 = *(const float4*)(s + 4);
            unsigned short o[8] = {f2bf(u0.x), f2bf(u0.y), f2bf(u0.z), f2bf(u0.w),
                                   f2bf(u1.x), f2bf(u1.y), f2bf(u1.z), f2bf(u1.w)};
            *(short8*)&As[r * 256 + ((c ^ (r & 7)) * 8)] = *(short8*)o;
        }
    } else {
        const unsigned short* xb = (const unsigned short*)x_in + (size_t)m0 * 256;
        #pragma unroll
        for (int i = 0; i < 4; ++i) {
            int j0 = i * 512 + wid * 64;   // wave-uniform chunk base
            int j = j0 + lane;
            int r = j >> 5;
            int c = j & 31;
            __builtin_amdgcn_global_load_lds(
                (const __attribute__((address_space(1))) unsigned int*)(xb + (size_t)r * 256 + ((c ^ (r & 7)) * 8)),
                (__attribute__((address_space(3))) unsigned int*)&As[(size_t)j0 * 8],
                16, 0, 0);
        }
    }
    __syncthreads();

    f32x4 acc[4][5];
    #pragma unroll
    for (int mf = 0; mf < 4; ++mf)
        #pragma unroll
        for (int g = 0; g < 5; ++g)
            acc[mf][g] = (f32x4){0.f, 0.f, 0.f, 0.f};

    // B-fragment base: W row n = g*128 + wid*16 + col, k = kg*8 + kc*32
    const unsigned short* wbase = Wb + (size_t)(wid * 16 + col) * 256 + kg * 8;

    #pragma unroll
    for (int kc = 0; kc < 8; ++kc) {
        short8 a[4];
        #pragma unroll
        for (int mf = 0; mf < 4; ++mf) {
            int ar = mf * 16 + col;
            int q = (kg + kc * 4) ^ (ar & 7);
            a[mf] = *(const short8*)&As[ar * 256 + q * 8];
        }
        #pragma unroll
        for (int g = 0; g < 5; ++g) {
            short8 bf = *(const short8*)(wbase + (size_t)g * 32768 + kc * 32);
            #pragma unroll
            for (int mf = 0; mf < 4; ++mf)
                acc[mf][g] = __builtin_amdgcn_mfma_f32_16x16x32_bf16(a[mf], bf, acc[mf][g], 0, 0, 0);
        }
    }

    const int d = wid * 16 + col;
    float bias[5];
    #pragma unroll
    for (int g = 0; g < 5; ++g) bias[g] = b[g * 128 + d];

    #pragma unroll
    for (int mf = 0; mf < 4; ++mf) {
        #pragma unroll
        for (int r = 0; r < 4; ++r) {
            const int P = m0 + mf * 16 + kg * 4 + r;
            if (P < n_par) {
                float iv = sigmoidf_(acc[mf][0][r] + bias[0]);
                float fl = sigmoidf_(acc[mf][1][r] + bias[1]);
                float fr = sigmoidf_(acc[mf][2][r] + bias[2]);
                float ov = sigmoidf_(acc[mf][3][r] + bias[3]);
                float gv = tanhf_(acc[mf][4][r] + bias[4]);
                float cl = 0.f, cr = 0.f;
                if (!FIRST) {
                    cl = c_in[(size_t)(2 * P) * 128 + d];
                    cr = c_in[(size_t)(2 * P + 1) * 128 + d];
                }
                float cn = fl * cl + fr * cr + iv * gv;
                float hn = ov * tanhf_(cn);
                c_out[(size_t)P * 128 + d] = cn;
                h_out[(size_t)P * 128 + d] = f2bf(hn);
            }
        }
    }
}

// Fused tail: levels 10..16 (per tree: 64,32,16,8,4,2,1 parents), one block per
// tree, levels looped in-LDS. Input = level-9 output (128 h/c rows per tree in
// global). Writes the tree's root h (f32) to roots[tree*128 ..].
__global__ __launch_bounds__(512)
void tail_kernel(const unsigned short* __restrict__ h_in,
                 const float* __restrict__ c_in,
                 const unsigned short* __restrict__ Wb,
                 const float* __restrict__ b,
                 float* __restrict__ roots) {
    __shared__ unsigned short Hs[8192];  // up to 64 parent h-rows x 128 (16 KB)
    __shared__ float Cs[8192];           // up to 64 parent c-rows x 128 (32 KB)

    const int t = threadIdx.x;
    const int lane = t & 63;
    const int wid = t >> 6;
    const int col = lane & 15;
    const int kg = lane >> 4;
    const int d = wid * 16 + col;
    const int tree = blockIdx.x;

    float bias[5];
    #pragma unroll
    for (int g = 0; g < 5; ++g) bias[g] = b[g * 128 + d];

    const unsigned short* hg = h_in + (size_t)tree * 128 * 128;
    const float* cg = c_in + (size_t)tree * 128 * 128;

    int parents = 64;
    for (int lvl = 0; lvl < 7; ++lvl) {
        f32x4 acc[4][5];
        #pragma unroll
        for (int mf = 0; mf < 4; ++mf)
            #pragma unroll
            for (int g = 0; g < 5; ++g)
                acc[mf][g] = (f32x4){0.f, 0.f, 0.f, 0.f};

        #pragma unroll
        for (int kc = 0; kc < 8; ++kc) {
            short8 a[4];
            #pragma unroll
            for (int mf = 0; mf < 4; ++mf) {
                int p = mf * 16 + col;
                if (lvl == 0) {
                    a[mf] = *(const short8*)(hg + (size_t)p * 256 + kg * 8 + kc * 32);
                } else {
                    int pr = p & (parents - 1);  // clamp to valid rows (<=31 here)
                    a[mf] = *(const short8*)&Hs[pr * 256 + kg * 8 + kc * 32];
                }
            }
            #pragma unroll
            for (int g = 0; g < 5; ++g) {
                short8 bf = *(const short8*)(Wb + (size_t)(g * 128 + d) * 256 + kg * 8 + kc * 32);
                #pragma unroll
                for (int mf = 0; mf < 4; ++mf)
                    acc[mf][g] = __builtin_amdgcn_mfma_f32_16x16x32_bf16(a[mf], bf, acc[mf][g], 0, 0, 0);
            }
        }

        // stage c children into regs (all reads before any write)
        float cl[4][4], cr[4][4];
        #pragma unroll
        for (int mf = 0; mf < 4; ++mf)
            #pragma unroll
            for (int r = 0; r < 4; ++r) {
                int P = mf * 16 + kg * 4 + r;
                if (lvl == 0) {
                    cl[mf][r] = cg[(size_t)(2 * P) * 128 + d];
                    cr[mf][r] = cg[(size_t)(2 * P + 1) * 128 + d];
                } else {
                    int Pr = P & (parents - 1);
                    cl[mf][r] = Cs[(2 * Pr) * 128 + d];
                    cr[mf][r] = Cs[(2 * Pr + 1) * 128 + d];
                }
            }
        __syncthreads();

        #pragma unroll
        for (int mf = 0; mf < 4; ++mf)
            #pragma unroll
            for (int r = 0; r < 4; ++r) {
                int P = mf * 16 + kg * 4 + r;
                if (P < parents) {
                    float iv = sigmoidf_(acc[mf][0][r] + bias[0]);
                    float fl = sigmoidf_(acc[mf][1][r] + bias[1]);
                    float fr = sigmoidf_(acc[mf][2][r] + bias[2]);
                    float ov = sigmoidf_(acc[mf][3][r] + bias[3]);
                    float gv = tanhf_(acc[mf][4][r] + bias[4]);
                    float cn = fl * cl[mf][r] + fr * cr[mf][r] + iv * gv;
                    float hn = ov * tanhf_(cn);
                    Cs[P * 128 + d] = cn;
                    Hs[P * 128 + d] = f2bf(hn);
                }
            }
        __syncthreads();
        parents >>= 1;
    }

    if (t < 128) roots[tree * 128 + t] = bf2f(Hs[t]);
}

// out[0:128] = mean of 4 f32 roots; out[128:256] = 0
__global__ void root_kernel(const float* __restrict__ roots, float* __restrict__ out) {
    int t = threadIdx.x;
    if (t < 128) {
        out[t] = 0.25f * (roots[t] + roots[128 + t] + roots[256 + t] + roots[384 + t]);
    } else if (t < 256) {
        out[t] = 0.0f;
    }
}

// leaves output row r -> [leaf_emb[r] (128 f32) | zeros (128)]
__global__ void copy_leaves_kernel(const float* __restrict__ leaf, float* __restrict__ out) {
    const float4* lf4 = (const float4*)leaf;
    float4* of4 = (float4*)(out + 256);
    const size_t total = (size_t)NRES * 64;
    for (size_t v = (size_t)blockIdx.x * blockDim.x + threadIdx.x; v < total;
         v += (size_t)gridDim.x * blockDim.x) {
        size_t r = v >> 6;
        int c = (int)(v & 63);
        float4 val = (c < 32) ? lf4[(r << 5) + c] : make_float4(0.f, 0.f, 0.f, 0.f);
        of4[v] = val;
    }
}

extern "C" void kernel_launch(void* const* d_in, const int* in_sizes, int n_in,
                              void* d_out, int out_size, void* d_ws, size_t ws_size,
                              hipStream_t stream) {
    const float* leaf = (const float*)d_in[0];
    const float* W_up = (const float*)d_in[1];
    const float* b_up = (const float*)d_in[2];
    float* out = (float*)d_out;
    char* base = (char*)d_out;

    // Scratch carved from d_out (fully overwritten by root + copy at the end):
    float* cA = (float*)(base);                                // 64 MiB
    float* cB = (float*)(base + 67108864);                     // 32 MiB
    unsigned short* hA = (unsigned short*)(base + 100663296);  // 32 MiB
    unsigned short* hB = (unsigned short*)(base + 134217728);  // 16 MiB
    unsigned short* Wb = (unsigned short*)(base + 150994944);  // 320 KiB
    float* roots = (float*)(base + 151322624);                 // 2 KiB

    convert_w_kernel<<<160, 256, 0, stream>>>(W_up, Wb);

    int n_par = NRES / 2;  // 131072
    level_kernel<true><<<n_par / 64, 512, 0, stream>>>(leaf, nullptr, Wb, b_up, hA, cA, n_par);

    const unsigned short* hin = hA;
    const float* cin = cA;
    unsigned short* ho = hB;
    float* co = cB;
    for (int lvl = 2; lvl <= 9; ++lvl) {
        n_par >>= 1;  // 65536 .. 512
        level_kernel<false><<<n_par / 64, 512, 0, stream>>>(hin, cin, Wb, b_up, ho, co, n_par);
        const unsigned short* th = hin;
        const float* tc = cin;
        hin = ho; cin = co;
        ho = (unsigned short*)th; co = (float*)tc;
    }
    // level-9 output (512 rows) is where hin/cin point now (hA/cA)
    tail_kernel<<<4, 512, 0, stream>>>(hin, cin, Wb, b_up, roots);
    root_kernel<<<1, 256, 0, stream>>>(roots, out);
    copy_leaves_kernel<<<4096, 256, 0, stream>>>(leaf, out);
}

// Round 5
// 517.993 us; speedup vs baseline: 1.4072x; 1.0904x over previous
//
#include <hip/hip_runtime.h>
#include <math.h>

#define DIM 128
#define NRES 262144

typedef __attribute__((ext_vector_type(8))) short short8;
typedef __attribute__((ext_vector_type(4))) float f32x4;

__device__ __forceinline__ float sigmoidf_(float x) {
    return 1.0f / (1.0f + __expf(-x));
}
__device__ __forceinline__ float tanhf_(float x) {
    return 1.0f - 2.0f / (__expf(2.0f * x) + 1.0f);
}
__device__ __forceinline__ unsigned short f2bf(float f) {
    unsigned int u = __float_as_uint(f);
    unsigned int r = u + 0x7FFFu + ((u >> 16) & 1u);
    return (unsigned short)(r >> 16);
}
__device__ __forceinline__ float bf2f(unsigned short s) {
    return __uint_as_float(((unsigned int)s) << 16);
}

// W f32 [640][256] -> bf16 [640][256]
__global__ void convert_w_kernel(const float* __restrict__ W, unsigned short* __restrict__ Wb) {
    int i = blockIdx.x * 256 + threadIdx.x;
    float4 v = ((const float4*)W)[i];
    unsigned short o[4] = {f2bf(v.x), f2bf(v.y), f2bf(v.z), f2bf(v.w)};
    *(ushort4*)(Wb + i * 4) = *(ushort4*)o;
}

// Persistent-W tree-LSTM level. A = x_in as [n_par][256]. 512 thr = 8 waves,
// wave w owns d-slice [16w,16w+16) for ALL 5 gates; its full-K B fragments
// live in 160 VGPRs (loaded once). Grid-stride m-loop over 32-row tiles;
// A double-buffered in LDS (2x16KB, chunk-XOR swizzle), staged one tile ahead
// (T3-minimum 2-phase: issue STAGE(t+1), compute(t), one barrier per tile).
template<bool FIRST>
__global__ __launch_bounds__(512, 2)
void level_kernel(const void* __restrict__ x_in,
                  const float* __restrict__ c_in,
                  const unsigned short* __restrict__ Wb,
                  const float* __restrict__ b,
                  unsigned short* __restrict__ h_out,
                  float* __restrict__ c_out,
                  int n_par) {
    __shared__ unsigned short As[2][8192];  // 2 x 16 KB

    const int t = threadIdx.x;
    const int lane = t & 63;
    const int wid = t >> 6;   // 0..7 = d-slice
    const int col = lane & 15;
    const int kg = lane >> 4;
    const int d = wid * 16 + col;
    const int stride = gridDim.x;
    const int tiles = n_par >> 5;  // n_par is a multiple of 32 (512..131072)

    if (blockIdx.x >= tiles) return;

    // ---- B resident in registers: 5 gates x 8 k-chunks x short8 = 160 VGPR
    short8 Breg[5][8];
    {
        const unsigned short* wbase = Wb + (size_t)d * 256 + kg * 8;
        #pragma unroll
        for (int g = 0; g < 5; ++g)
            #pragma unroll
            for (int kc = 0; kc < 8; ++kc)
                Breg[g][kc] = *(const short8*)(wbase + (size_t)g * 32768 + kc * 32);
    }

    float bias[5];
    #pragma unroll
    for (int g = 0; g < 5; ++g) bias[g] = b[g * 128 + d];

#define STAGE_GL(bufp, ti_) do {                                                     \
    const unsigned short* xb = (const unsigned short*)x_in + ((size_t)(ti_) * 32) * 256; \
    _Pragma("unroll")                                                                \
    for (int i_ = 0; i_ < 2; ++i_) {                                                 \
        int j0 = i_ * 512 + wid * 64;                                                \
        int j = j0 + lane;                                                           \
        int r = j >> 5, c = j & 31;                                                  \
        __builtin_amdgcn_global_load_lds(                                            \
            (const __attribute__((address_space(1))) unsigned int*)(xb + (size_t)r * 256 + ((c ^ (r & 7)) * 8)), \
            (__attribute__((address_space(3))) unsigned int*)((bufp) + j0 * 8),      \
            16, 0, 0);                                                               \
    }                                                                                \
} while (0)

#define STAGE_F_LOAD(ti_) do {                                                       \
    const float* xf = (const float*)x_in + ((size_t)(ti_) * 32) * 256;               \
    int j = t, r = j >> 5, c = j & 31;                                               \
    s0 = *(const float4*)(xf + r * 256 + c * 8);                                     \
    s1 = *(const float4*)(xf + r * 256 + c * 8 + 4);                                 \
    j = 512 + t; r = j >> 5; c = j & 31;                                             \
    s2 = *(const float4*)(xf + r * 256 + c * 8);                                     \
    s3 = *(const float4*)(xf + r * 256 + c * 8 + 4);                                 \
} while (0)

#define STAGE_F_WRITE(bufp) do {                                                     \
    int j = t, r = j >> 5, c = j & 31;                                               \
    unsigned short o0[8] = {f2bf(s0.x), f2bf(s0.y), f2bf(s0.z), f2bf(s0.w),          \
                            f2bf(s1.x), f2bf(s1.y), f2bf(s1.z), f2bf(s1.w)};         \
    *(short8*)((bufp) + r * 256 + ((c ^ (r & 7)) * 8)) = *(short8*)o0;               \
    j = 512 + t; r = j >> 5; c = j & 31;                                             \
    unsigned short o1[8] = {f2bf(s2.x), f2bf(s2.y), f2bf(s2.z), f2bf(s2.w),          \
                            f2bf(s3.x), f2bf(s3.y), f2bf(s3.z), f2bf(s3.w)};         \
    *(short8*)((bufp) + r * 256 + ((c ^ (r & 7)) * 8)) = *(short8*)o1;               \
} while (0)

#define COMPUTE(bufp, ti_) do {                                                      \
    const int m0 = (ti_) * 32;                                                       \
    f32x4 acc[2][5];                                                                 \
    _Pragma("unroll")                                                                \
    for (int mf = 0; mf < 2; ++mf)                                                   \
        _Pragma("unroll")                                                            \
        for (int g = 0; g < 5; ++g) acc[mf][g] = (f32x4){0.f, 0.f, 0.f, 0.f};        \
    _Pragma("unroll")                                                                \
    for (int kc = 0; kc < 8; ++kc) {                                                 \
        short8 a0, a1;                                                               \
        { int q = (kc * 4 + kg) ^ (col & 7);                                         \
          a0 = *(const short8*)((bufp) + (col) * 256 + q * 8);                       \
          a1 = *(const short8*)((bufp) + (16 + col) * 256 + q * 8); }                \
        _Pragma("unroll")                                                            \
        for (int g = 0; g < 5; ++g) {                                                \
            acc[0][g] = __builtin_amdgcn_mfma_f32_16x16x32_bf16(a0, Breg[g][kc], acc[0][g], 0, 0, 0); \
            acc[1][g] = __builtin_amdgcn_mfma_f32_16x16x32_bf16(a1, Breg[g][kc], acc[1][g], 0, 0, 0); \
        }                                                                            \
    }                                                                                \
    _Pragma("unroll")                                                                \
    for (int mf = 0; mf < 2; ++mf)                                                   \
        _Pragma("unroll")                                                            \
        for (int r4 = 0; r4 < 4; ++r4) {                                             \
            const int P = m0 + mf * 16 + kg * 4 + r4;                                \
            float iv = sigmoidf_(acc[mf][0][r4] + bias[0]);                          \
            float fl = sigmoidf_(acc[mf][1][r4] + bias[1]);                          \
            float fr = sigmoidf_(acc[mf][2][r4] + bias[2]);                          \
            float ov = sigmoidf_(acc[mf][3][r4] + bias[3]);                          \
            float gv = tanhf_(acc[mf][4][r4] + bias[4]);                             \
            float cl = 0.f, cr = 0.f;                                                \
            if (!FIRST) {                                                            \
                cl = c_in[(size_t)(2 * P) * 128 + d];                                \
                cr = c_in[(size_t)(2 * P + 1) * 128 + d];                            \
            }                                                                        \
            float cn = fl * cl + fr * cr + iv * gv;                                  \
            float hn = ov * tanhf_(cn);                                              \
            c_out[(size_t)P * 128 + d] = cn;                                         \
            h_out[(size_t)P * 128 + d] = f2bf(hn);                                   \
        }                                                                            \
} while (0)

    float4 s0, s1, s2, s3;
    int ti = blockIdx.x;
    int cur = 0;

    if (FIRST) {
        STAGE_F_LOAD(ti);
        STAGE_F_WRITE(As[0]);
    } else {
        STAGE_GL(As[0], ti);
    }
    __syncthreads();

    for (; ti < tiles; ti += stride) {
        const int tn = ti + stride;
        if (FIRST) {
            if (tn < tiles) STAGE_F_LOAD(tn);
            COMPUTE(As[cur], ti);
            if (tn < tiles) STAGE_F_WRITE(As[cur ^ 1]);
        } else {
            if (tn < tiles) STAGE_GL(As[cur ^ 1], tn);
            COMPUTE(As[cur], ti);
        }
        __syncthreads();
        cur ^= 1;
    }
#undef STAGE_GL
#undef STAGE_F_LOAD
#undef STAGE_F_WRITE
#undef COMPUTE
}

// Fused tail: levels 10..16 (64->1 parents per tree), one block per tree.
__global__ __launch_bounds__(512)
void tail_kernel(const unsigned short* __restrict__ h_in,
                 const float* __restrict__ c_in,
                 const unsigned short* __restrict__ Wb,
                 const float* __restrict__ b,
                 float* __restrict__ roots) {
    __shared__ unsigned short Hs[8192];
    __shared__ float Cs[8192];

    const int t = threadIdx.x;
    const int lane = t & 63;
    const int wid = t >> 6;
    const int col = lane & 15;
    const int kg = lane >> 4;
    const int d = wid * 16 + col;
    const int tree = blockIdx.x;

    float bias[5];
    #pragma unroll
    for (int g = 0; g < 5; ++g) bias[g] = b[g * 128 + d];

    const unsigned short* hg = h_in + (size_t)tree * 128 * 128;
    const float* cg = c_in + (size_t)tree * 128 * 128;

    int parents = 64;
    for (int lvl = 0; lvl < 7; ++lvl) {
        f32x4 acc[4][5];
        #pragma unroll
        for (int mf = 0; mf < 4; ++mf)
            #pragma unroll
            for (int g = 0; g < 5; ++g)
                acc[mf][g] = (f32x4){0.f, 0.f, 0.f, 0.f};

        #pragma unroll
        for (int kc = 0; kc < 8; ++kc) {
            short8 a[4];
            #pragma unroll
            for (int mf = 0; mf < 4; ++mf) {
                int p = mf * 16 + col;
                if (lvl == 0) {
                    a[mf] = *(const short8*)(hg + (size_t)p * 256 + kg * 8 + kc * 32);
                } else {
                    int pr = p & (parents - 1);
                    a[mf] = *(const short8*)&Hs[pr * 256 + kg * 8 + kc * 32];
                }
            }
            #pragma unroll
            for (int g = 0; g < 5; ++g) {
                short8 bf = *(const short8*)(Wb + (size_t)(g * 128 + d) * 256 + kg * 8 + kc * 32);
                #pragma unroll
                for (int mf = 0; mf < 4; ++mf)
                    acc[mf][g] = __builtin_amdgcn_mfma_f32_16x16x32_bf16(a[mf], bf, acc[mf][g], 0, 0, 0);
            }
        }

        float cl[4][4], cr[4][4];
        #pragma unroll
        for (int mf = 0; mf < 4; ++mf)
            #pragma unroll
            for (int r = 0; r < 4; ++r) {
                int P = mf * 16 + kg * 4 + r;
                if (lvl == 0) {
                    cl[mf][r] = cg[(size_t)(2 * P) * 128 + d];
                    cr[mf][r] = cg[(size_t)(2 * P + 1) * 128 + d];
                } else {
                    int Pr = P & (parents - 1);
                    cl[mf][r] = Cs[(2 * Pr) * 128 + d];
                    cr[mf][r] = Cs[(2 * Pr + 1) * 128 + d];
                }
            }
        __syncthreads();

        #pragma unroll
        for (int mf = 0; mf < 4; ++mf)
            #pragma unroll
            for (int r = 0; r < 4; ++r) {
                int P = mf * 16 + kg * 4 + r;
                if (P < parents) {
                    float iv = sigmoidf_(acc[mf][0][r] + bias[0]);
                    float fl = sigmoidf_(acc[mf][1][r] + bias[1]);
                    float fr = sigmoidf_(acc[mf][2][r] + bias[2]);
                    float ov = sigmoidf_(acc[mf][3][r] + bias[3]);
                    float gv = tanhf_(acc[mf][4][r] + bias[4]);
                    float cn = fl * cl[mf][r] + fr * cr[mf][r] + iv * gv;
                    float hn = ov * tanhf_(cn);
                    Cs[P * 128 + d] = cn;
                    Hs[P * 128 + d] = f2bf(hn);
                }
            }
        __syncthreads();
        parents >>= 1;
    }

    if (t < 128) roots[tree * 128 + t] = bf2f(Hs[t]);
}

__global__ void root_kernel(const float* __restrict__ roots, float* __restrict__ out) {
    int t = threadIdx.x;
    if (t < 128) {
        out[t] = 0.25f * (roots[t] + roots[128 + t] + roots[256 + t] + roots[384 + t]);
    } else if (t < 256) {
        out[t] = 0.0f;
    }
}

__global__ void copy_leaves_kernel(const float* __restrict__ leaf, float* __restrict__ out) {
    const float4* lf4 = (const float4*)leaf;
    float4* of4 = (float4*)(out + 256);
    const size_t total = (size_t)NRES * 64;
    for (size_t v = (size_t)blockIdx.x * blockDim.x + threadIdx.x; v < total;
         v += (size_t)gridDim.x * blockDim.x) {
        size_t r = v >> 6;
        int c = (int)(v & 63);
        float4 val = (c < 32) ? lf4[(r << 5) + c] : make_float4(0.f, 0.f, 0.f, 0.f);
        of4[v] = val;
    }
}

extern "C" void kernel_launch(void* const* d_in, const int* in_sizes, int n_in,
                              void* d_out, int out_size, void* d_ws, size_t ws_size,
                              hipStream_t stream) {
    const float* leaf = (const float*)d_in[0];
    const float* W_up = (const float*)d_in[1];
    const float* b_up = (const float*)d_in[2];
    float* out = (float*)d_out;
    char* base = (char*)d_out;

    float* cA = (float*)(base);                                // 64 MiB
    float* cB = (float*)(base + 67108864);                     // 32 MiB
    unsigned short* hA = (unsigned short*)(base + 100663296);  // 32 MiB
    unsigned short* hB = (unsigned short*)(base + 134217728);  // 16 MiB
    unsigned short* Wb = (unsigned short*)(base + 150994944);  // 320 KiB
    float* roots = (float*)(base + 151322624);                 // 2 KiB

    convert_w_kernel<<<160, 256, 0, stream>>>(W_up, Wb);

    int n_par = NRES / 2;  // 131072
    {
        int tiles = n_par >> 5;
        int grid = tiles < 256 ? tiles : 256;
        level_kernel<true><<<grid, 512, 0, stream>>>(leaf, nullptr, Wb, b_up, hA, cA, n_par);
    }

    const unsigned short* hin = hA;
    const float* cin = cA;
    unsigned short* ho = hB;
    float* co = cB;
    for (int lvl = 2; lvl <= 9; ++lvl) {
        n_par >>= 1;  // 65536 .. 512
        int tiles = n_par >> 5;
        int grid = tiles < 256 ? tiles : 256;
        level_kernel<false><<<grid, 512, 0, stream>>>(hin, cin, Wb, b_up, ho, co, n_par);
        const unsigned short* th = hin;
        const float* tc = cin;
        hin = ho; cin = co;
        ho = (unsigned short*)th; co = (float*)tc;
    }
    tail_kernel<<<4, 512, 0, stream>>>(hin, cin, Wb, b_up, roots);
    root_kernel<<<1, 256, 0, stream>>>(roots, out);
    copy_leaves_kernel<<<4096, 256, 0, stream>>>(leaf, out);
}

// Round 6
// 418.988 us; speedup vs baseline: 1.7397x; 1.2363x over previous
//
#include <hip/hip_runtime.h>
#include <math.h>

#define DIM 128
#define NRES 262144

typedef __attribute__((ext_vector_type(8))) short short8;
typedef __attribute__((ext_vector_type(4))) float f32x4;

__device__ __forceinline__ float sigmoidf_(float x) {
    return 1.0f / (1.0f + __expf(-x));
}
__device__ __forceinline__ float tanhf_(float x) {
    return 1.0f - 2.0f / (__expf(2.0f * x) + 1.0f);
}
__device__ __forceinline__ unsigned short f2bf(float f) {
    unsigned int u = __float_as_uint(f);
    unsigned int r = u + 0x7FFFu + ((u >> 16) & 1u);
    return (unsigned short)(r >> 16);
}
__device__ __forceinline__ float bf2f(unsigned short s) {
    return __uint_as_float(((unsigned int)s) << 16);
}

// W f32 [640][256] -> bf16 [640][256]
__global__ void convert_w_kernel(const float* __restrict__ W, unsigned short* __restrict__ Wb) {
    int i = blockIdx.x * 256 + threadIdx.x;
    float4 v = ((const float4*)W)[i];
    unsigned short o[4] = {f2bf(v.x), f2bf(v.y), f2bf(v.z), f2bf(v.w)};
    *(ushort4*)(Wb + i * 4) = *(ushort4*)o;
}

// ---------------- fused multi-level tree-LSTM ----------------
// Block = 512 thr = 8 waves; wave w owns d-slice [16w,16w+16) for all 5 gates
// (W resident in 160 VGPRs). Block takes in_rows input h-rows (= in_rows/2
// A-rows of 256) and reduces `levels` levels entirely in LDS; only the final
// rows go to global. h in LDS uses a fragment-major layout: chunk (A-row r,
// k-chunk c) lives at ushort offset ((r>>4)*512 + (c>>2)*64 + (c&3)*16 +
// (r&15))*8 -> a wave's 64 fragments per (kc) are 1024 contiguous bytes
// (zero-conflict ds_read_b128) and the staging destination is linear
// (global_load_lds-compatible). c in LDS as bf16, stride 148 (anti-conflict).
//
// LDS map (ushort units):
//   H0 [0,16384)      up to 64 A-rows
//   H1 [16384,24576)  up to 32 A-rows
//   C1 [24576,34048)  up to 64 c-rows (stride 148)
//   C0 [34048,38784)  up to 32 c-rows
//   ROOT [38784,39808) 512 f32
#define H0_OFF 0
#define H1_OFF 16384
#define C1_OFF 24576
#define C0_OFF 34048
#define ROOT_OFF 38784
#define CSTRIDE 148

template<bool LEAF, bool LASTPASS>
__global__ __launch_bounds__(512, 2)
void fused_kernel(const void* __restrict__ x_in,
                  const unsigned short* __restrict__ c_in,   // bf16 children c (null if LEAF)
                  const unsigned short* __restrict__ Wb,
                  const float* __restrict__ bvec,
                  unsigned short* __restrict__ h_out,        // null if LASTPASS
                  unsigned short* __restrict__ c_out,
                  float* __restrict__ out,   // LEAF: write-through; LASTPASS: final out
                  int in_rows, int levels) {
    __shared__ __align__(16) unsigned short lds[39808];

    const int t = threadIdx.x;
    const int lane = t & 63;
    const int wid = t >> 6;
    const int col = lane & 15;
    const int kg = lane >> 4;
    const int d = wid * 16 + col;
    const int frows = in_rows >> levels;

    // ---- W resident: 5 gates x 8 k-chunks x short8 = 160 VGPR
    short8 Breg[5][8];
    {
        const unsigned short* wbase = Wb + (size_t)d * 256 + kg * 8;
        #pragma unroll
        for (int g = 0; g < 5; ++g)
            #pragma unroll
            for (int kc = 0; kc < 8; ++kc)
                Breg[g][kc] = *(const short8*)(wbase + (size_t)g * 32768 + kc * 32);
    }
    float bias[5];
    #pragma unroll
    for (int g = 0; g < 5; ++g) bias[g] = bvec[g * 128 + d];

    // ---- stage input h into H0 (fragment-major; LDS dst linear in chunk id)
    const int nchunk = in_rows * 16;  // (in_rows/2 A-rows) x 32 chunks
    if (LEAF) {
        const float* xf = (const float*)x_in + (size_t)blockIdx.x * in_rows * 128;
        float* outw = out + 256 + (size_t)blockIdx.x * in_rows * 256;
        for (int m = t; m < nchunk; m += 512) {
            int b2 = m >> 9, rem = m & 511;
            int kc = rem >> 6, kgi = (rem >> 4) & 3, ci = rem & 15;
            int row = b2 * 16 + ci;   // A-row
            int c = kc * 4 + kgi;     // k-chunk 0..31
            const float* s = xf + (size_t)row * 256 + c * 8;
            float4 u0 = *(const float4*)s;
            float4 u1 = *(const float4*)(s + 4);
            unsigned short o[8] = {f2bf(u0.x), f2bf(u0.y), f2bf(u0.z), f2bf(u0.w),
                                   f2bf(u1.x), f2bf(u1.y), f2bf(u1.z), f2bf(u1.w)};
            *(short8*)&lds[H0_OFF + m * 8] = *(short8*)o;
            // write-through leaves output: row l = 2*row + (c>=16), elems (c&15)*8..
            int l = 2 * row + (c >> 4);
            float* wdst = outw + (size_t)l * 256 + (c & 15) * 8;
            *(float4*)wdst = u0;
            *(float4*)(wdst + 4) = u1;
            *(float4*)(wdst + 128) = make_float4(0.f, 0.f, 0.f, 0.f);
            *(float4*)(wdst + 132) = make_float4(0.f, 0.f, 0.f, 0.f);
        }
    } else {
        const unsigned short* xb = (const unsigned short*)x_in + (size_t)blockIdx.x * in_rows * 128;
        for (int m0 = 0; m0 < nchunk; m0 += 512) {
            int mw = m0 + wid * 64;
            if (mw < nchunk) {  // wave-uniform (nchunk multiple of 64)
                int m = mw + lane;
                int b2 = m >> 9, rem = m & 511;
                int kc = rem >> 6, kgi = (rem >> 4) & 3, ci = rem & 15;
                int row = b2 * 16 + ci;
                int c = kc * 4 + kgi;
                __builtin_amdgcn_global_load_lds(
                    (const __attribute__((address_space(1))) unsigned int*)(xb + (size_t)row * 256 + c * 8),
                    (__attribute__((address_space(3))) unsigned int*)&lds[H0_OFF + mw * 8],
                    16, 0, 0);
            }
        }
    }
    __syncthreads();

#define EPI(ACC, MF) do {                                                              \
    _Pragma("unroll")                                                                  \
    for (int r4 = 0; r4 < 4; ++r4) {                                                   \
        const int P = ch * 32 + (MF) * 16 + kg * 4 + r4;                               \
        if (P < parents) {                                                             \
            float iv = sigmoidf_(ACC[0][r4] + bias[0]);                                \
            float fl = sigmoidf_(ACC[1][r4] + bias[1]);                                \
            float fr = sigmoidf_(ACC[2][r4] + bias[2]);                                \
            float ov = sigmoidf_(ACC[3][r4] + bias[3]);                                \
            float gv = tanhf_(ACC[4][r4] + bias[4]);                                   \
            float cl = 0.f, cr = 0.f;                                                  \
            if (lvl == 0) {                                                            \
                if (!LEAF) {                                                           \
                    size_t cb = ((size_t)blockIdx.x * in_rows + 2 * P) * 128 + d;      \
                    cl = bf2f(c_in[cb]); cr = bf2f(c_in[cb + 128]);                    \
                }                                                                      \
            } else {                                                                   \
                cl = bf2f(lds[cs + (2 * P) * CSTRIDE + d]);                            \
                cr = bf2f(lds[cs + (2 * P + 1) * CSTRIDE + d]);                        \
            }                                                                          \
            float cn = fl * cl + fr * cr + iv * gv;                                    \
            float hn = ov * tanhf_(cn);                                                \
            if (last) {                                                                \
                if (LASTPASS) {                                                        \
                    ((float*)(lds + ROOT_OFF))[P * 128 + d] = hn;                      \
                } else {                                                               \
                    size_t oo = ((size_t)blockIdx.x * frows + P) * 128 + d;            \
                    h_out[oo] = f2bf(hn);                                              \
                    c_out[oo] = f2bf(cn);                                              \
                }                                                                      \
            } else {                                                                   \
                int rw = P >> 1;                                                       \
                int cc2 = (P & 1) * 16 + (d >> 3);                                     \
                lds[hd + (rw >> 4) * 4096 + (cc2 >> 2) * 512 + (cc2 & 3) * 128         \
                    + (rw & 15) * 8 + (d & 7)] = f2bf(hn);                             \
                lds[cd + P * CSTRIDE + d] = f2bf(cn);                                  \
            }                                                                          \
        }                                                                              \
    }                                                                                  \
} while (0)

    int hs = H0_OFF, hd = H1_OFF, cs = C1_OFF, cd = C1_OFF;
    int parents = in_rows >> 1;
    for (int lvl = 0; lvl < levels; ++lvl) {
        const bool last = (lvl == levels - 1);
        const int nch = (parents + 31) >> 5;
        for (int ch = 0; ch < nch; ++ch) {
            const bool hiv = (ch * 32 + 16) < parents;
            f32x4 acc0[5], acc1[5];
            #pragma unroll
            for (int g = 0; g < 5; ++g) {
                acc0[g] = (f32x4){0.f, 0.f, 0.f, 0.f};
                acc1[g] = (f32x4){0.f, 0.f, 0.f, 0.f};
            }
            #pragma unroll
            for (int kc = 0; kc < 8; ++kc) {
                short8 a0 = *(const short8*)&lds[hs + (2 * ch) * 4096 + kc * 512 + kg * 128 + col * 8];
                #pragma unroll
                for (int g = 0; g < 5; ++g)
                    acc0[g] = __builtin_amdgcn_mfma_f32_16x16x32_bf16(a0, Breg[g][kc], acc0[g], 0, 0, 0);
                if (hiv) {
                    short8 a1 = *(const short8*)&lds[hs + (2 * ch + 1) * 4096 + kc * 512 + kg * 128 + col * 8];
                    #pragma unroll
                    for (int g = 0; g < 5; ++g)
                        acc1[g] = __builtin_amdgcn_mfma_f32_16x16x32_bf16(a1, Breg[g][kc], acc1[g], 0, 0, 0);
                }
            }
            EPI(acc0, 0);
            if (hiv) EPI(acc1, 1);
        }
        __syncthreads();
        int tmp = hs; hs = hd; hd = tmp;
        if (lvl == 0) { cs = C1_OFF; cd = C0_OFF; }
        else { tmp = cs; cs = cd; cd = tmp; }
        parents >>= 1;
    }
#undef EPI

    if (LASTPASS) {
        const float* rf = (const float*)(lds + ROOT_OFF);
        if (t < 128) out[t] = 0.25f * (rf[t] + rf[128 + t] + rf[256 + t] + rf[384 + t]);
        else if (t < 256) out[t] = 0.0f;
    }
}

extern "C" void kernel_launch(void* const* d_in, const int* in_sizes, int n_in,
                              void* d_out, int out_size, void* d_ws, size_t ws_size,
                              hipStream_t stream) {
    const float* leaf = (const float*)d_in[0];
    const float* W_up = (const float*)d_in[1];
    const float* b_up = (const float*)d_in[2];
    float* out = (float*)d_out;
    char* ws = (char*)d_ws;

    unsigned short* Wb = (unsigned short*)ws;                 // 327,680 B
    unsigned short* h1 = (unsigned short*)(ws + 0x80000);     // 2048 rows x 128 bf16
    unsigned short* c1 = (unsigned short*)(ws + 0x100000);    // 2048 rows
    unsigned short* h2 = (unsigned short*)(ws + 0x180000);    // 16 rows
    unsigned short* c2 = (unsigned short*)(ws + 0x181000);    // 16 rows

    convert_w_kernel<<<160, 256, 0, stream>>>(W_up, Wb);

    // pass 1: 262144 leaves -> 2048 level-7 nodes (7 levels) + leaves write-through
    fused_kernel<true, false><<<2048, 512, 0, stream>>>(
        leaf, nullptr, Wb, b_up, h1, c1, out, 128, 7);

    // pass 2: 2048 -> 16 level-14 nodes (7 levels)
    fused_kernel<false, false><<<16, 512, 0, stream>>>(
        h1, c1, Wb, b_up, h2, c2, nullptr, 128, 7);

    // pass 3: 16 -> 4 roots (2 levels) + mean + zero tail of out[0:256]
    fused_kernel<false, true><<<1, 512, 0, stream>>>(
        h2, c2, Wb, b_up, nullptr, nullptr, out, 16, 2);
}